// Round 1
// baseline (468.493 us; speedup 1.0000x reference)
//
#include <hip/hip_runtime.h>

#define TT 512
#define BB 256
#define DD 128
#define HH 128
#define QQ 8

struct Params {
    const float* x;
    const float* W[4];
    const float* b[4];
    const float* th[4];
    const float* U[4];
    const float* cb[4];
    float* out;
};

__device__ __forceinline__ float rcp_f(float x)  { return __builtin_amdgcn_rcpf(x); }
__device__ __forceinline__ float exp2_f(float x) { return __builtin_amdgcn_exp2f(x); }

// DPP move for sum-butterflies (old=0, bound_ctrl=on; all lanes valid for these perms)
template<int CTRL>
__device__ __forceinline__ float dpp_mov(float x) {
    int r = __builtin_amdgcn_update_dpp(0, __float_as_int(x), CTRL, 0xF, 0xF, true);
    return __int_as_float(r);
}
// DPP with multiplicative-identity fallback: masked/invalid lanes receive 1.0f.
template<int CTRL, int RM>
__device__ __forceinline__ float dpp_mul1(float x) {
    int r = __builtin_amdgcn_update_dpp(0x3f800000 /*1.0f*/, __float_as_int(x),
                                        CTRL, RM, 0xF, false);
    return __int_as_float(r);
}
#define RDLANE(v, l) __int_as_float(__builtin_amdgcn_readlane(__float_as_int(v), (l)))

// Barrier without vmcnt drain (LDS ordering only) — global loads/stores stay in flight.
__device__ __forceinline__ void bar_lds() {
    asm volatile("s_waitcnt lgkmcnt(0)\n\ts_barrier" ::: "memory");
}

// One block per batch element; 4 waves; wave w owns gate w for Z + U-expansion.
// SINGLE barrier per step: pre[] is double-buffered and transposed across waves;
// the E phase (activations + cell update) is recomputed redundantly by EVERY wave
// into a private hbuf copy, so the h round-trip is intra-wave (in-order LDS pipe,
// no barrier, no cross-wave skew). zx(t+1) is per-wave-gate, kept in a register,
// and issued after E so its LDS reads hide under E's pre-read latency.
// LDS pad: slot(k) = k + 4*(k>>5) -> conflict-free + 16B-aligned b128 slices.
__global__ __launch_bounds__(256, 1) void qlstm(Params p) {
    __shared__ __align__(16) float xbuf[2][8][144]; // staged x rows (padded)
    __shared__ __align__(16) float hb[4][144];      // per-wave private h copy (padded)
    __shared__ __align__(16) float pre[2][4][128];  // double-buffered gate preacts (scaled)

    const int tid = threadIdx.x;
    const int bId = blockIdx.x;
    const int ln  = tid & 63;
    const int wv  = tid >> 6;        // wave id == gate id
    const int qub = ln >> 3;         // qubit (octet)
    const int part8 = ln & 7;        // 16-float slice within 128

    // ---- weights: octet layout for both halves (part8 covers 16 floats) ----
    float Wh[16], Wx[16];
    {
        const float* Wg = p.W[wv] + qub * (DD + HH);
        #pragma unroll
        for (int j = 0; j < 16; ++j) Wx[j] = Wg[part8 * 16 + j];
        #pragma unroll
        for (int j = 0; j < 16; ++j) Wh[j] = Wg[DD + part8 * 16 + j];
    }
    const float breg = p.b[wv][qub] + p.th[wv][qub];  // fused bias+theta

    // gates f,i,o: pre' = -log2e * pre  -> sigm = rcp(1+exp2(pre'))
    // gate  g    : pre' = 2*log2e * pre -> tanh = 1 - 2*rcp(1+exp2(pre'))
    const float esc = (wv == 2) ? 2.885390081777927f : -1.442695040888963f;
    float Ua[8], Ub[8];
    #pragma unroll
    for (int j = 0; j < 8; ++j) {
        Ua[j] = p.U[wv][ln * QQ + j] * esc;
        Ub[j] = p.U[wv][(ln + 64) * QQ + j] * esc;
    }
    const float cba = p.cb[wv][ln] * esc;
    const float cbb = p.cb[wv][ln + 64] * esc;

    // padded slots for h writes: slot(ln), slot(ln+64) = slot(ln)+72
    const int sa = ln + 4 * (ln >> 5);
    const int sb = sa + 72;
    float csta = 0.f, cstb = 0.f, hna = 0.f, hnb = 0.f;
    hb[wv][sa] = 0.f;
    hb[wv][sb] = 0.f;

    // ---- x staging: all 4 waves, wave wv covers rows 2wv,2wv+1 of each chunk ----
    const int xrow_ = 2 * wv + (ln >> 5);
    const int xcol  = (ln & 31) * 4;
    const int xslot = xcol + 4 * (xcol >> 5);
    {   // chunk 0, synchronous
        float4 v0 = *(const float4*)(p.x + ((size_t)xrow_ * BB + bId) * DD + xcol);
        *(float4*)&xbuf[0][xrow_][xslot] = v0;
    }
    bar_lds();

    const int lsoff = 16 * part8 + 4 * (part8 >> 1);   // padded slice base
    const float* hsrc = &hb[wv][lsoff];

    // ---- preamble zx(0) ----
    float zxc;
    {
        const float* xr0 = &xbuf[0][0][lsoff];
        float b0 = 0.f, b1 = 0.f, b2 = 0.f, b3 = 0.f;
        #pragma unroll
        for (int i = 0; i < 4; ++i) {
            float4 c4 = *(const float4*)(xr0 + 4 * i);
            b0 = fmaf(Wx[4*i+0], c4.x, b0);
            b1 = fmaf(Wx[4*i+1], c4.y, b1);
            b2 = fmaf(Wx[4*i+2], c4.z, b2);
            b3 = fmaf(Wx[4*i+3], c4.w, b3);
        }
        float z = (b0 + b1) + (b2 + b3);
        z += dpp_mov<0xB1>(z);
        z += dpp_mov<0x4E>(z);
        z += dpp_mov<0x141>(z);
        zxc = z;
    }

    float4 xr = make_float4(0.f, 0.f, 0.f, 0.f);

    #pragma unroll 8
    for (int t = 0; t < TT; ++t) {
        // ---- x prefetch issue: 6 steps of slack before xbuf refill at t&7==6 ----
        if ((t & 7) == 0) {
            const int tch = (t >> 3) + 1;
            if (tch < TT / 8) {
                const int row = tch * 8 + xrow_;
                xr = *(const float4*)(p.x + ((size_t)row * BB + bId) * DD + xcol);
            }
        }

        // ---- Z(t): zh = W[wv][qub] . h from OWN hbuf copy (intra-wave, no barrier) ----
        float a0 = 0.f, a1 = 0.f, a2 = 0.f, a3 = 0.f;
        #pragma unroll
        for (int i = 0; i < 4; ++i) {
            float4 c4 = *(const float4*)(hsrc + 4 * i);
            a0 = fmaf(Wh[4*i+0], c4.x, a0);
            a1 = fmaf(Wh[4*i+1], c4.y, a1);
            a2 = fmaf(Wh[4*i+2], c4.z, a2);
            a3 = fmaf(Wh[4*i+3], c4.w, a3);
        }
        float acc = (a0 + a1) + (a2 + a3);
        acc += dpp_mov<0xB1>(acc);      // xor1 (quad_perm)
        acc += dpp_mov<0x4E>(acc);      // xor2 (quad_perm)
        acc += dpp_mov<0x141>(acc);     // row_half_mirror: cross-quad within octet
        acc += zxc + breg;

        // ---- Qgate: cos + dual stride-8 product scan (DPP) + readlane bcast ----
        const float cv = __cosf(acc);          // all 8 lanes of octet hold c_q
        float v = cv;
        v *= dpp_mul1<0x118, 0xF>(v);          // row_shr:8 (guard -> *1)
        v *= dpp_mul1<0x142, 0xA>(v);          // row_bcast15 -> rows 1,3
        v *= dpp_mul1<0x143, 0xC>(v);          // row_bcast31 -> rows 2,3
        float u = (ln < 8) ? 1.f : cv;         // scan excluding qubit 0
        u *= dpp_mul1<0x118, 0xF>(u);
        u *= dpp_mul1<0x142, 0xA>(u);
        u *= dpp_mul1<0x143, 0xC>(u);
        const float q0 = RDLANE(u, 63);        // prod_{j>=1} c_j
        const float q1 = RDLANE(v, 8);
        const float q2 = RDLANE(v, 16);
        const float q3 = RDLANE(v, 24);
        const float q4 = RDLANE(v, 32);
        const float q5 = RDLANE(v, 40);
        const float q6 = RDLANE(v, 48);
        const float q7 = RDLANE(v, 56);

        // ---- U expansion (scaled): pre'[wv][h] for h=ln and h=ln+64 ----
        float pa = fmaf(Ua[0], q0, cba); float pb = fmaf(Ub[0], q0, cbb);
        pa = fmaf(Ua[1], q1, pa);        pb = fmaf(Ub[1], q1, pb);
        pa = fmaf(Ua[2], q2, pa);        pb = fmaf(Ub[2], q2, pb);
        pa = fmaf(Ua[3], q3, pa);        pb = fmaf(Ub[3], q3, pb);
        pa = fmaf(Ua[4], q4, pa);        pb = fmaf(Ub[4], q4, pb);
        pa = fmaf(Ua[5], q5, pa);        pb = fmaf(Ub[5], q5, pb);
        pa = fmaf(Ua[6], q6, pa);        pb = fmaf(Ub[6], q6, pb);
        pa = fmaf(Ua[7], q7, pa);        pb = fmaf(Ub[7], q7, pb);
        pre[t & 1][wv][ln]      = pa;
        pre[t & 1][wv][64 + ln] = pb;

        // ---- xbuf refill one chunk-step early (other buffer; read starts t+2) ----
        if ((t & 7) == 6) {
            const int tch = (t >> 3) + 1;
            if (tch < TT / 8) {
                *(float4*)&xbuf[tch & 1][xrow_][xslot] = xr;
            }
        }

        bar_lds();   // THE barrier: pre[t&1] (+ refilled xbuf) visible to all waves

        // ---- E(t): redundant on all 4 waves into private hbuf copy ----
        const float pf_a = pre[t & 1][0][ln];
        const float pi_a = pre[t & 1][1][ln];
        const float pg_a = pre[t & 1][2][ln];
        const float po_a = pre[t & 1][3][ln];
        const float pf_b = pre[t & 1][0][64 + ln];
        const float pi_b = pre[t & 1][1][64 + ln];
        const float pg_b = pre[t & 1][2][64 + ln];
        const float po_b = pre[t & 1][3][64 + ln];

        float fga = rcp_f(1.f + exp2_f(pf_a));
        float iga = rcp_f(1.f + exp2_f(pi_a));
        float gga = 1.f - 2.f * rcp_f(1.f + exp2_f(pg_a));
        float oga = rcp_f(1.f + exp2_f(po_a));
        csta = fmaf(fga, csta, iga * gga);
        const float tca = 1.f - 2.f * rcp_f(1.f + exp2_f(csta * 2.885390081777927f));
        hna = oga * tca;

        float fgb = rcp_f(1.f + exp2_f(pf_b));
        float igb = rcp_f(1.f + exp2_f(pi_b));
        float ggb = 1.f - 2.f * rcp_f(1.f + exp2_f(pg_b));
        float ogb = rcp_f(1.f + exp2_f(po_b));
        cstb = fmaf(fgb, cstb, igb * ggb);
        const float tcb = 1.f - 2.f * rcp_f(1.f + exp2_f(cstb * 2.885390081777927f));
        hnb = ogb * tcb;

        hb[wv][sa] = hna;     // own copy: next Z(t+1) reads it intra-wave
        hb[wv][sb] = hnb;

        if (wv == 0) {        // single wave streams the output
            float* o = p.out + (size_t)(t * BB + bId) * HH;
            o[ln]      = hna;
            o[ln + 64] = hnb;
        }

        // ---- zx(t+1): per-wave-gate, in-register; LDS reads hide under E ----
        float zxn = 0.f;
        if (t < TT - 1) {
            const int tn = t + 1;
            const float* xr0 = &xbuf[(tn >> 3) & 1][tn & 7][lsoff];
            float b0 = 0.f, b1 = 0.f, b2 = 0.f, b3 = 0.f;
            #pragma unroll
            for (int i = 0; i < 4; ++i) {
                float4 c4 = *(const float4*)(xr0 + 4 * i);
                b0 = fmaf(Wx[4*i+0], c4.x, b0);
                b1 = fmaf(Wx[4*i+1], c4.y, b1);
                b2 = fmaf(Wx[4*i+2], c4.z, b2);
                b3 = fmaf(Wx[4*i+3], c4.w, b3);
            }
            float z = (b0 + b1) + (b2 + b3);
            z += dpp_mov<0xB1>(z);
            z += dpp_mov<0x4E>(z);
            z += dpp_mov<0x141>(z);
            zxn = z;
        }
        zxc = zxn;
        // NO second barrier: pre is double-buffered, hbuf is wave-private,
        // xbuf buffers alternate with >=2 barriers between conflicting accesses.
    }

    // ---- tail: hx, cx ----
    if (wv == 0) {
        float* o = p.out + (size_t)TT * BB * HH;
        o[(size_t)bId * HH + ln]             = hna;
        o[(size_t)bId * HH + ln + 64]        = hnb;
        o[(size_t)(BB + bId) * HH + ln]      = csta;
        o[(size_t)(BB + bId) * HH + ln + 64] = cstb;
    }
}

extern "C" void kernel_launch(void* const* d_in, const int* in_sizes, int n_in,
                              void* d_out, int out_size, void* d_ws, size_t ws_size,
                              hipStream_t stream) {
    (void)in_sizes; (void)n_in; (void)out_size; (void)d_ws; (void)ws_size;
    Params p;
    p.x = (const float*)d_in[0];
    for (int g = 0; g < 4; ++g) {
        p.W[g]  = (const float*)d_in[1 + 5 * g + 0];
        p.b[g]  = (const float*)d_in[1 + 5 * g + 1];
        p.th[g] = (const float*)d_in[1 + 5 * g + 2];
        p.U[g]  = (const float*)d_in[1 + 5 * g + 3];
        p.cb[g] = (const float*)d_in[1 + 5 * g + 4];
    }
    p.out = (float*)d_out;
    hipLaunchKernelGGL(qlstm, dim3(BB), dim3(256), 0, stream, p);
}

// Round 2
// 362.006 us; speedup vs baseline: 1.2942x; 1.2942x over previous
//
#include <hip/hip_runtime.h>

#define TT 512
#define BB 256
#define DD 128
#define HH 128
#define QQ 8

struct Params {
    const float* x;
    const float* W[4];
    const float* b[4];
    const float* th[4];
    const float* U[4];
    const float* cb[4];
    float* out;
};

__device__ __forceinline__ float rcp_f(float x)  { return __builtin_amdgcn_rcpf(x); }
__device__ __forceinline__ float exp2_f(float x) { return __builtin_amdgcn_exp2f(x); }

// DPP move for sum-butterflies (old=0, bound_ctrl=on; all lanes valid for xor perms)
template<int CTRL>
__device__ __forceinline__ float dpp_mov(float x) {
    int r = __builtin_amdgcn_update_dpp(0, __float_as_int(x), CTRL, 0xF, 0xF, true);
    return __int_as_float(r);
}
// DPP with multiplicative-identity fallback: masked/invalid lanes receive 1.0f.
template<int CTRL, int RM>
__device__ __forceinline__ float dpp_mul1(float x) {
    int r = __builtin_amdgcn_update_dpp(0x3f800000 /*1.0f*/, __float_as_int(x),
                                        CTRL, RM, 0xF, false);
    return __int_as_float(r);
}
#define RDLANE(v, l) __int_as_float(__builtin_amdgcn_readlane(__float_as_int(v), (l)))

// Barrier without vmcnt drain (LDS ordering only) — global loads/stores stay in flight.
__device__ __forceinline__ void bar_lds() {
    asm volatile("s_waitcnt lgkmcnt(0)\n\ts_barrier" ::: "memory");
}

// One block per batch element; 4 waves; wave w owns gate w (f,i,g,o).
// Proven 2-barrier split: phase A (all waves: Z+qgate+Uexp) | bar | phase B
// (waves 0-1: E epilogue; waves 2-3: pipelined zx(t+1) + x staging) | bar.
// R1 lesson: single-barrier/E-dup variants forfeit the E∥zx wave-parallelism
// at higher cost (trans duplication + LDS pipe clog) — keep the split.
// This round: shorten A's serial depth (Uexp tree), stream LDS loads
// back-to-back, incremental out addressing.
// LDS pad: slot(k) = k + 4*(k>>5) -> conflict-free + 16B-aligned b128 slices.
__global__ __launch_bounds__(256, 1) void qlstm(Params p) {
    __shared__ __align__(16) float xbuf[2][8][144]; // staged x rows (padded)
    __shared__ __align__(16) float hbuf[144];       // h_{t-1} (padded)
    __shared__ float pre[512];                      // gate preactivations (scaled)
    __shared__ float zxbuf[2][32];                  // pipelined x-half of z

    const int tid = threadIdx.x;
    const int bId = blockIdx.x;
    const int ln  = tid & 63;
    const int wv  = tid >> 6;        // wave id == gate id
    const int qub = ln >> 3;         // qubit (octet)
    const int part8 = ln & 7;        // 16-float h-slice

    // ---- zh weights: W[wv][qub][128 + 16*part8 + j] ----
    float Wh[16];
    {
        const float* Wg = p.W[wv] + qub * (DD + HH) + DD + part8 * 16;
        #pragma unroll
        for (int j = 0; j < 16; ++j) Wh[j] = Wg[j];
    }
    const float breg = p.b[wv][qub] + p.th[wv][qub];  // fused bias+theta

    // ---- zx weights (waves 2-3): gate gz, qubit qz, 32-float x-slice pz ----
    const int gz = 2 * (wv - 2) + (ln >> 5);
    const int qz = (ln >> 2) & 7;
    const int pz = ln & 3;
    float Wx[32];
    if (wv >= 2) {
        const float* Wg = p.W[gz] + qz * (DD + HH) + pz * 32;
        #pragma unroll
        for (int j = 0; j < 32; ++j) Wx[j] = Wg[j];
    }

    // ---- U expansion constants, pre-scaled for exp2-based activations ----
    // gates f,i,o: pre' = -log2e * pre  -> sigm = rcp(1+exp2(pre'))
    // gate  g    : pre' = 2*log2e * pre -> tanh = 1 - 2*rcp(1+exp2(pre'))
    const float esc = (wv == 2) ? 2.885390081777927f : -1.442695040888963f;
    float Ua[8], Ub[8];
    #pragma unroll
    for (int j = 0; j < 8; ++j) {
        Ua[j] = p.U[wv][ln * QQ + j] * esc;
        Ub[j] = p.U[wv][(ln + 64) * QQ + j] * esc;
    }
    const float cba = p.cb[wv][ln] * esc;
    const float cbb = p.cb[wv][ln + 64] * esc;

    float cst = 0.f;      // cell state, owned by tid<128 (h=tid)
    float hn_last = 0.f;

    if (tid < 128) hbuf[tid + 4 * (tid >> 5)] = 0.f;

    // ---- x staging (wave 3): lane covers col=(ln&31)*4, rows 2j+(ln>>5) ----
    const int xc_col  = (ln & 31) * 4;
    const int xc_half = ln >> 5;
    const int xc_slot = xc_col + 4 * (xc_col >> 5);
    float4 xr[4];
    #pragma unroll
    for (int j = 0; j < 4; ++j) xr[j] = make_float4(0.f, 0.f, 0.f, 0.f);

    if (wv == 3) {  // chunk 0 (steps 0..7), synchronous
        #pragma unroll
        for (int j = 0; j < 4; ++j) {
            const int row = 2 * j + xc_half;
            float4 v = *(const float4*)(p.x + ((size_t)row * BB + bId) * DD + xc_col);
            *(float4*)&xbuf[0][row][xc_slot] = v;
        }
    }
    __syncthreads();

    // ---- preamble zx(0) by waves 2-3 ----
    if (wv >= 2) {
        const float* xrow = &xbuf[0][0][36 * pz];
        float b0 = 0.f, b1 = 0.f, b2 = 0.f, b3 = 0.f;
        #pragma unroll
        for (int i = 0; i < 8; ++i) {
            float4 c4 = *(const float4*)(xrow + 4 * i);
            b0 = fmaf(Wx[4*i+0], c4.x, b0);
            b1 = fmaf(Wx[4*i+1], c4.y, b1);
            b2 = fmaf(Wx[4*i+2], c4.z, b2);
            b3 = fmaf(Wx[4*i+3], c4.w, b3);
        }
        float zx2 = (b0 + b1) + (b2 + b3);
        zx2 += dpp_mov<0xB1>(zx2);
        zx2 += dpp_mov<0x4E>(zx2);
        if ((ln & 3) == 0) zxbuf[0][8 * gz + qz] = zx2;
    }
    __syncthreads();

    const float* hsrc = &hbuf[16 * part8 + 4 * (part8 >> 1)];
    const size_t orow_step = (size_t)BB * HH;
    size_t orow = (size_t)bId * HH + tid;     // used by tid<128 only

    #pragma unroll 8
    for (int t = 0; t < TT; ++t) {
        // ---- Z: issue independent LDS reads first (zxs + 4x b128 h), stream pipe ----
        const float zxs = zxbuf[t & 1][8 * wv + qub];   // broadcast over octet
        const float4 h0 = ((const float4*)hsrc)[0];
        const float4 h1 = *(const float4*)(hsrc + 4);
        const float4 h2 = *(const float4*)(hsrc + 8);
        const float4 h3 = *(const float4*)(hsrc + 12);

        // ---- x prefetch issue (wave 3): 6 steps of slack to consume at refill ----
        if (((t & 7) == 0) && wv == 3) {
            const int tch = (t >> 3) + 1;
            if (tch < TT / 8) {
                #pragma unroll
                for (int j = 0; j < 4; ++j) {
                    const int row = tch * 8 + 2 * j + xc_half;
                    xr[j] = *(const float4*)(p.x + ((size_t)row * BB + bId) * DD + xc_col);
                }
            }
        }

        float a0 = Wh[0] * h0.x, a1 = Wh[1] * h0.y, a2 = Wh[2] * h0.z, a3 = Wh[3] * h0.w;
        a0 = fmaf(Wh[4],  h1.x, a0); a1 = fmaf(Wh[5],  h1.y, a1);
        a2 = fmaf(Wh[6],  h1.z, a2); a3 = fmaf(Wh[7],  h1.w, a3);
        a0 = fmaf(Wh[8],  h2.x, a0); a1 = fmaf(Wh[9],  h2.y, a1);
        a2 = fmaf(Wh[10], h2.z, a2); a3 = fmaf(Wh[11], h2.w, a3);
        a0 = fmaf(Wh[12], h3.x, a0); a1 = fmaf(Wh[13], h3.y, a1);
        a2 = fmaf(Wh[14], h3.z, a2); a3 = fmaf(Wh[15], h3.w, a3);
        float acc = (a0 + a1) + (a2 + a3);
        // 8-lane sum reduce (DPP butterflies)
        acc += dpp_mov<0xB1>(acc);
        acc += dpp_mov<0x4E>(acc);
        acc += dpp_mov<0x141>(acc);
        acc += zxs + breg;

        // ---- Qgate: cos + dual stride-8 product scan (DPP) + readlane bcast ----
        const float cv = __cosf(acc);           // all 8 lanes of octet hold c_q
        float v = cv;
        v *= dpp_mul1<0x118, 0xF>(v);           // row_shr:8 (guard -> *1)
        v *= dpp_mul1<0x142, 0xA>(v);           // row_bcast15 -> rows 1,3
        v *= dpp_mul1<0x143, 0xC>(v);           // row_bcast31 -> rows 2,3
        float u = (ln < 8) ? 1.f : cv;          // scan excluding qubit 0
        u *= dpp_mul1<0x118, 0xF>(u);
        u *= dpp_mul1<0x142, 0xA>(u);
        u *= dpp_mul1<0x143, 0xC>(u);
        const float q0 = RDLANE(u, 63);         // prod_{j>=1} c_j
        const float q1 = RDLANE(v, 8);
        const float q2 = RDLANE(v, 16);
        const float q3 = RDLANE(v, 24);
        const float q4 = RDLANE(v, 32);
        const float q5 = RDLANE(v, 40);
        const float q6 = RDLANE(v, 48);
        const float q7 = RDLANE(v, 56);

        // ---- U expansion (scaled), tree form: depth 5 instead of 8 ----
        float a01 = fmaf(Ua[1], q1, Ua[0] * q0);
        float b01 = fmaf(Ub[1], q1, Ub[0] * q0);
        float a23 = fmaf(Ua[3], q3, Ua[2] * q2);
        float b23 = fmaf(Ub[3], q3, Ub[2] * q2);
        float a45 = fmaf(Ua[5], q5, Ua[4] * q4);
        float b45 = fmaf(Ub[5], q5, Ub[4] * q4);
        float a67 = fmaf(Ua[7], q7, Ua[6] * q6);
        float b67 = fmaf(Ub[7], q7, Ub[6] * q6);
        float pa = ((a01 + a23) + (a45 + a67)) + cba;
        float pb = ((b01 + b23) + (b45 + b67)) + cbb;
        pre[wv * 128 + ln]      = pa;
        pre[wv * 128 + 64 + ln] = pb;

        bar_lds();   // barrier 1: pre[] (+ zxbuf written last E) visible

        // ---- E (waves 0-1) in parallel with zx(t+1) (waves 2-3) ----
        if (tid < 128) {
            // own-gate preact is already in-register (wave0: pa=f@h=ln; wave1: pb=i@h=64+ln)
            float p_f = (wv == 0) ? pa : pre[tid];
            float p_i = (wv == 1) ? pb : pre[128 + tid];
            float p_g = pre[256 + tid];
            float p_o = pre[384 + tid];
            float fg = rcp_f(1.f + exp2_f(p_f));
            float ig = rcp_f(1.f + exp2_f(p_i));
            float gg = fmaf(-2.f, rcp_f(1.f + exp2_f(p_g)), 1.f);
            float og = rcp_f(1.f + exp2_f(p_o));
            cst = fmaf(fg, cst, ig * gg);
            float tc = fmaf(-2.f, rcp_f(1.f + exp2_f(cst * 2.885390081777927f)), 1.f);
            float hn = og * tc;
            hn_last = hn;
            hbuf[tid + 4 * (tid >> 5)] = hn;
            p.out[orow] = hn;                    // issue-only
            orow += orow_step;
        } else {
            // xbuf refill one chunk-step early (t&7==6) so zx(t+1) at t&7==7 is safe
            if (wv == 3 && (t & 7) == 6) {
                const int tch = (t >> 3) + 1;
                if (tch < TT / 8) {
                    #pragma unroll
                    for (int j = 0; j < 4; ++j) {
                        const int row = 2 * j + xc_half;
                        *(float4*)&xbuf[tch & 1][row][xc_slot] = xr[j];
                    }
                }
            }
            // pipelined zx for step t+1: stream all 8 b128 reads, then FMA
            if (t < TT - 1) {
                const int tn = t + 1;
                const float* xrow = &xbuf[(tn >> 3) & 1][tn & 7][36 * pz];
                float4 c[8];
                #pragma unroll
                for (int i = 0; i < 8; ++i) c[i] = *(const float4*)(xrow + 4 * i);
                float b0 = Wx[0] * c[0].x, b1 = Wx[1] * c[0].y;
                float b2 = Wx[2] * c[0].z, b3 = Wx[3] * c[0].w;
                #pragma unroll
                for (int i = 1; i < 8; ++i) {
                    b0 = fmaf(Wx[4*i+0], c[i].x, b0);
                    b1 = fmaf(Wx[4*i+1], c[i].y, b1);
                    b2 = fmaf(Wx[4*i+2], c[i].z, b2);
                    b3 = fmaf(Wx[4*i+3], c[i].w, b3);
                }
                float zx2 = (b0 + b1) + (b2 + b3);
                zx2 += dpp_mov<0xB1>(zx2);
                zx2 += dpp_mov<0x4E>(zx2);
                if ((ln & 3) == 0) zxbuf[tn & 1][8 * gz + qz] = zx2;
            }
        }
        bar_lds();   // barrier 2: hbuf / xbuf / zxbuf ready for next step
    }

    // ---- tail: hx, cx ----
    if (tid < 128) {
        p.out[(size_t)TT * BB * HH + (size_t)bId * HH + tid] = hn_last;
        p.out[(size_t)TT * BB * HH + (size_t)BB * HH + (size_t)bId * HH + tid] = cst;
    }
}

extern "C" void kernel_launch(void* const* d_in, const int* in_sizes, int n_in,
                              void* d_out, int out_size, void* d_ws, size_t ws_size,
                              hipStream_t stream) {
    (void)in_sizes; (void)n_in; (void)out_size; (void)d_ws; (void)ws_size;
    Params p;
    p.x = (const float*)d_in[0];
    for (int g = 0; g < 4; ++g) {
        p.W[g]  = (const float*)d_in[1 + 5 * g + 0];
        p.b[g]  = (const float*)d_in[1 + 5 * g + 1];
        p.th[g] = (const float*)d_in[1 + 5 * g + 2];
        p.U[g]  = (const float*)d_in[1 + 5 * g + 3];
        p.cb[g] = (const float*)d_in[1 + 5 * g + 4];
    }
    p.out = (float*)d_out;
    hipLaunchKernelGGL(qlstm, dim3(BB), dim3(256), 0, stream, p);
}